// Round 3
// baseline (1106.649 us; speedup 1.0000x reference)
//
#include <hip/hip_runtime.h>
#include <cmath>

static constexpr int NN  = 50000;   // nodes
static constexpr int NE  = 800000;  // edges
static constexpr int HID = 64;
static constexpr int BB  = 64;      // batch
static constexpr int TT  = 200;     // seq len
static constexpr int LH  = 128;     // lstm hidden
static constexpr int G4  = 512;     // 4*LH

__device__ __forceinline__ float sigmoid_fast(float x) {
    return __fdividef(1.f, 1.f + __expf(-x));
}
__device__ __forceinline__ float tanh_fast(float x) {
    return __fdividef(2.f, 1.f + __expf(-2.f * x)) - 1.f;
}

// ================= CSR build =================
__global__ __launch_bounds__(256) void hist_kernel(const int* __restrict__ dsts,
                                                   int* __restrict__ deg) {
    int i = blockIdx.x * 256 + threadIdx.x;
    if (i < NE) atomicAdd(&deg[dsts[i]], 1);
}

// single-block exclusive scan of deg[NN] -> rowptr[NN+1], head[NN]
__global__ __launch_bounds__(1024) void scan_kernel(const int* __restrict__ deg,
                                                    int* __restrict__ rowptr,
                                                    int* __restrict__ head) {
    __shared__ int wsums[16];
    __shared__ int s_carry;
    const int tid  = threadIdx.x;
    const int lane = tid & 63;
    const int wv   = tid >> 6;
    if (tid == 0) s_carry = 0;
    __syncthreads();
    for (int base = 0; base < NN; base += 1024) {
        const int idx = base + tid;
        int v = (idx < NN) ? deg[idx] : 0;
        int x = v;
        #pragma unroll
        for (int off = 1; off < 64; off <<= 1) {
            int y = __shfl_up(x, off);
            if (lane >= off) x += y;
        }
        if (lane == 63) wsums[wv] = x;
        __syncthreads();
        if (tid < 16) {
            int s = wsums[tid];
            #pragma unroll
            for (int off = 1; off < 16; off <<= 1) {
                int y = __shfl_up(s, off);
                if (tid >= off) s += y;
            }
            wsums[tid] = s;
        }
        __syncthreads();
        const int wave_off = wv ? wsums[wv - 1] : 0;
        const int carry = s_carry;
        const int excl = carry + wave_off + x - v;
        if (idx < NN) { rowptr[idx] = excl; head[idx] = excl; }
        __syncthreads();
        if (tid == 0) s_carry = carry + wsums[15];
        __syncthreads();
    }
    if (threadIdx.x == 0) rowptr[NN] = s_carry;
}

__global__ __launch_bounds__(256) void scatter_kernel(const int* __restrict__ srcs,
                                                      const int* __restrict__ dsts,
                                                      int* __restrict__ head,
                                                      int2* __restrict__ sorted) {
    int e = blockIdx.x * 256 + threadIdx.x;
    if (e < NE) {
        int d = dsts[e];
        int pos = atomicAdd(&head[d], 1);
        sorted[pos] = make_int2(e, srcs[e]);
    }
}

// ========= fused edge pass, CSR by dst, no atomics =========
// one wave per node: agg[n] = sum_{e in in(n)} relu(EA[e]@W^T + b + h[src(e)])
__global__ __launch_bounds__(256) void edge_agg_kernel(
    const float* __restrict__ h_in,
    const float* __restrict__ ea,
    const float* __restrict__ W,     // [64][64] W[c][k]
    const float* __restrict__ bias,  // [64]
    const int*   __restrict__ rowptr,
    const int2*  __restrict__ sorted,
    float*       __restrict__ agg)
{
    __shared__ float4 stage[4][64];  // per wave: 4 edges x 64 ch
    const int lane = threadIdx.x & 63;
    const int wid  = threadIdx.x >> 6;

    float w[64];
    {
        const float4* wf = (const float4*)(W + lane * 64);
        #pragma unroll
        for (int k4 = 0; k4 < 16; ++k4) {
            float4 v = wf[k4];
            w[4*k4+0] = v.x; w[4*k4+1] = v.y; w[4*k4+2] = v.z; w[4*k4+3] = v.w;
        }
    }
    const float bc = bias[lane];
    const float4* eaf = (const float4*)ea;

    const int gw = blockIdx.x * 4 + wid;
    const int nw = gridDim.x * 4;
    for (int n = gw; n < NN; n += nw) {
        const int ofs = rowptr[n];
        const int deg = rowptr[n + 1] - ofs;
        float acc = 0.f;
        for (int c = 0; c < deg; c += 4) {
            const int rem = deg - c;
            if (rem >= 4) {
                int2 es = sorted[ofs + c + (lane >> 4)];
                stage[wid][lane] = eaf[(size_t)es.x * 16 + (lane & 15)];
                // prefetch the 4 h rows while FMAs run
                float hv[4];
                #pragma unroll
                for (int j = 0; j < 4; ++j) {
                    int sj = __shfl(es.y, j << 4);
                    hv[j] = h_in[(size_t)sj * HID + lane];
                }
                asm volatile("s_waitcnt lgkmcnt(0)" ::: "memory");
                const float4* st = &stage[wid][0];
                #pragma unroll
                for (int j = 0; j < 4; ++j) {
                    float aE = bc;
                    #pragma unroll
                    for (int k4 = 0; k4 < 16; ++k4) {
                        float4 v = st[j*16 + k4];
                        aE = fmaf(v.x, w[4*k4+0], aE);
                        aE = fmaf(v.y, w[4*k4+1], aE);
                        aE = fmaf(v.z, w[4*k4+2], aE);
                        aE = fmaf(v.w, w[4*k4+3], aE);
                    }
                    float m = aE + hv[j];
                    acc += m > 0.f ? m : 0.f;
                }
            } else {
                int pick = lane >> 4; if (pick >= rem) pick = rem - 1;
                int2 es = sorted[ofs + c + pick];
                stage[wid][lane] = eaf[(size_t)es.x * 16 + (lane & 15)];
                asm volatile("s_waitcnt lgkmcnt(0)" ::: "memory");
                const float4* st = &stage[wid][0];
                for (int j = 0; j < rem; ++j) {
                    int sj = __shfl(es.y, j << 4);
                    float aE = bc;
                    #pragma unroll
                    for (int k4 = 0; k4 < 16; ++k4) {
                        float4 v = st[j*16 + k4];
                        aE = fmaf(v.x, w[4*k4+0], aE);
                        aE = fmaf(v.y, w[4*k4+1], aE);
                        aE = fmaf(v.z, w[4*k4+2], aE);
                        aE = fmaf(v.w, w[4*k4+3], aE);
                    }
                    float m = aE + h_in[(size_t)sj * HID + lane];
                    acc += m > 0.f ? m : 0.f;
                }
            }
        }
        agg[(size_t)n * HID + lane] = acc;
    }
}

// ---------------- node pass ----------------
__global__ __launch_bounds__(256) void node_kernel(
    const float* __restrict__ h_in,
    const float* __restrict__ agg,
    const float* __restrict__ W1, const float* __restrict__ b1,
    const float* __restrict__ W2, const float* __restrict__ b2,
    const float* __restrict__ epsp,
    const float* __restrict__ lnS, const float* __restrict__ lnB,
    float*       __restrict__ h_out)
{
    __shared__ float zbuf[4][64];
    __shared__ float tbuf[4][64];
    const int lane = threadIdx.x & 63;
    const int wid  = threadIdx.x >> 6;

    float w1[64], w2[64];
    {
        const float4* wf1 = (const float4*)(W1 + lane * 64);
        const float4* wf2 = (const float4*)(W2 + lane * 64);
        #pragma unroll
        for (int k4 = 0; k4 < 16; ++k4) {
            float4 a = wf1[k4], b = wf2[k4];
            w1[4*k4+0]=a.x; w1[4*k4+1]=a.y; w1[4*k4+2]=a.z; w1[4*k4+3]=a.w;
            w2[4*k4+0]=b.x; w2[4*k4+1]=b.y; w2[4*k4+2]=b.z; w2[4*k4+3]=b.w;
        }
    }
    const float b1c = b1[lane], b2c = b2[lane];
    const float sC = lnS[lane], bC = lnB[lane];
    const float epv = 1.f + epsp[0];

    const int gw = blockIdx.x * 4 + wid;
    const int nw = gridDim.x * 4;
    for (int n = gw; n < NN; n += nw) {
        float z = epv * h_in[(size_t)n*HID + lane] + agg[(size_t)n*HID + lane];
        zbuf[wid][lane] = z;
        asm volatile("s_waitcnt lgkmcnt(0)" ::: "memory");
        float acc = b1c;
        {
            const float4* zf = (const float4*)&zbuf[wid][0];
            #pragma unroll
            for (int k4 = 0; k4 < 16; ++k4) {
                float4 v = zf[k4];
                acc = fmaf(v.x, w1[4*k4+0], acc);
                acc = fmaf(v.y, w1[4*k4+1], acc);
                acc = fmaf(v.z, w1[4*k4+2], acc);
                acc = fmaf(v.w, w1[4*k4+3], acc);
            }
        }
        acc = acc > 0.f ? acc : 0.f;
        tbuf[wid][lane] = acc;
        asm volatile("s_waitcnt lgkmcnt(0)" ::: "memory");
        float acc2 = b2c;
        {
            const float4* tf = (const float4*)&tbuf[wid][0];
            #pragma unroll
            for (int k4 = 0; k4 < 16; ++k4) {
                float4 v = tf[k4];
                acc2 = fmaf(v.x, w2[4*k4+0], acc2);
                acc2 = fmaf(v.y, w2[4*k4+1], acc2);
                acc2 = fmaf(v.z, w2[4*k4+2], acc2);
                acc2 = fmaf(v.w, w2[4*k4+3], acc2);
            }
        }
        float s1 = acc2, s2 = acc2 * acc2;
        #pragma unroll
        for (int off = 32; off >= 1; off >>= 1) {
            s1 += __shfl_xor(s1, off);
            s2 += __shfl_xor(s2, off);
        }
        float mu  = s1 * (1.f/64.f);
        float var = s2 * (1.f/64.f) - mu * mu;
        float r   = rsqrtf(var + 1e-5f);
        float o   = (acc2 - mu) * r * sC + bC;
        h_out[(size_t)n*HID + lane] = o > 0.f ? o : 0.f;
    }
}

// ---------------- prep: W2T transpose + selp = b_ih + sel @ W_ih[:, :64]^T ----------------
__global__ __launch_bounds__(512) void prep_kernel(
    const float* __restrict__ Wih,   // [512][96]
    const float* __restrict__ bih,   // [512]
    const float* __restrict__ h2,    // [NN][64]
    const int*   __restrict__ nidx,  // [64]
    float*       __restrict__ W2T,   // [32][512]
    float*       __restrict__ selp)  // [64][512]
{
    const int g = threadIdx.x;
    if (blockIdx.x == BB) {
        #pragma unroll
        for (int k = 0; k < 32; ++k)
            W2T[k * G4 + g] = Wih[g * 96 + 64 + k];
    } else {
        const int b = blockIdx.x;
        __shared__ float hrow[64];
        if (g < 64) hrow[g] = h2[(size_t)nidx[b] * HID + g];
        __syncthreads();
        float acc = bih[g];
        #pragma unroll
        for (int k = 0; k < 64; ++k)
            acc = fmaf(hrow[k], Wih[g * 96 + k], acc);
        selp[b * G4 + g] = acc;
    }
}

// ---------------- xp[t][b][g] = selp[b][g] + x_seq[b][t] @ W2T[:,g] ----------------
__global__ __launch_bounds__(512) void xp_kernel(
    const float* __restrict__ xseq,  // [B][T][32]
    const float* __restrict__ selp,  // [B][512]
    const float* __restrict__ W2T,   // [32][512]
    float*       __restrict__ xp)    // [T][B][512]
{
    const int g   = threadIdx.x;
    const int row = blockIdx.x;      // row = t*64 + b
    const int t   = row >> 6;
    const int b   = row & 63;
    __shared__ float xs[32];
    if (g < 32) xs[g] = xseq[((size_t)b * TT + t) * 32 + g];
    __syncthreads();
    float acc = selp[b * G4 + g];
    #pragma unroll
    for (int k = 0; k < 32; ++k)
        acc = fmaf(xs[k], W2T[k * G4 + g], acc);
    xp[(size_t)row * G4 + g] = acc;
}

// ---------------- LSTM recurrence + final LN + fc ----------------
__global__ __launch_bounds__(512) void lstm_kernel(
    const float* __restrict__ xp,    // [T][B][512]
    const float* __restrict__ Whh,   // [512][128]
    const float* __restrict__ bhh,   // [512]
    const float* __restrict__ lnS, const float* __restrict__ lnB,  // [128]
    const float* __restrict__ fcW,   // [1][128]
    const float* __restrict__ fcb,   // [1]
    float*       __restrict__ out)   // [64]
{
    const int g = threadIdx.x;   // gate index 0..511
    const int b = blockIdx.x;    // batch row
    const int j = g & 127;       // hidden unit for elementwise phase
    const int gt = g >> 7;       // gate type (wave-uniform)

    float w[128];
    {
        const float4* wf = (const float4*)(Whh + (size_t)g * LH);
        #pragma unroll
        for (int k4 = 0; k4 < 32; ++k4) {
            float4 v = wf[k4];
            w[4*k4+0]=v.x; w[4*k4+1]=v.y; w[4*k4+2]=v.z; w[4*k4+3]=v.w;
        }
    }
    const float bg = bhh[g];

    __shared__ float h_lds[LH];
    __shared__ float gates[G4];
    if (g < LH) h_lds[g] = 0.f;
    float c = 0.f;
    __syncthreads();

    float xv = xp[(size_t)b * G4 + g];   // t=0 slice

    for (int t = 0; t < TT; ++t) {
        const int tn = (t + 1 < TT) ? t + 1 : t;
        const float xv_next = xp[((size_t)tn * BB + b) * G4 + g];

        float a0 = 0.f, a1 = 0.f, a2 = 0.f, a3 = 0.f;
        const float4* h4 = (const float4*)h_lds;
        #pragma unroll
        for (int k4 = 0; k4 < 32; k4 += 4) {
            float4 v0 = h4[k4+0], v1 = h4[k4+1], v2 = h4[k4+2], v3 = h4[k4+3];
            a0 = fmaf(v0.x, w[4*k4+ 0], a0); a0 = fmaf(v0.y, w[4*k4+ 1], a0);
            a0 = fmaf(v0.z, w[4*k4+ 2], a0); a0 = fmaf(v0.w, w[4*k4+ 3], a0);
            a1 = fmaf(v1.x, w[4*k4+ 4], a1); a1 = fmaf(v1.y, w[4*k4+ 5], a1);
            a1 = fmaf(v1.z, w[4*k4+ 6], a1); a1 = fmaf(v1.w, w[4*k4+ 7], a1);
            a2 = fmaf(v2.x, w[4*k4+ 8], a2); a2 = fmaf(v2.y, w[4*k4+ 9], a2);
            a2 = fmaf(v2.z, w[4*k4+10], a2); a2 = fmaf(v2.w, w[4*k4+11], a2);
            a3 = fmaf(v3.x, w[4*k4+12], a3); a3 = fmaf(v3.y, w[4*k4+13], a3);
            a3 = fmaf(v3.z, w[4*k4+14], a3); a3 = fmaf(v3.w, w[4*k4+15], a3);
        }
        float acc = xv + bg + ((a0 + a1) + (a2 + a3));

        float act = (gt == 2) ? tanh_fast(acc) : sigmoid_fast(acc);
        gates[g] = act;
        __syncthreads();

        float iv = gates[j];
        float fv = gates[j + LH];
        float gv = gates[j + 2*LH];
        float ov = gates[j + 3*LH];
        c = fmaf(fv, c, iv * gv);
        float hv = ov * tanh_fast(c);
        if (g < LH) h_lds[j] = hv;
        __syncthreads();

        xv = xv_next;
    }

    if (g < 64) {
        float h0 = h_lds[g], h1 = h_lds[g + 64];
        float s1 = h0 + h1, s2 = h0*h0 + h1*h1;
        #pragma unroll
        for (int off = 32; off >= 1; off >>= 1) {
            s1 += __shfl_xor(s1, off);
            s2 += __shfl_xor(s2, off);
        }
        float mu  = s1 * (1.f/128.f);
        float var = s2 * (1.f/128.f) - mu * mu;
        float r   = rsqrtf(var + 1e-5f);
        float p = ((h0 - mu)*r*lnS[g]      + lnB[g])      * fcW[g]
                + ((h1 - mu)*r*lnS[g + 64] + lnB[g + 64]) * fcW[g + 64];
        #pragma unroll
        for (int off = 32; off >= 1; off >>= 1) p += __shfl_xor(p, off);
        if (g == 0) out[b] = p + fcb[0];
    }
}

extern "C" void kernel_launch(void* const* d_in, const int* in_sizes, int n_in,
                              void* d_out, int out_size, void* d_ws, size_t ws_size,
                              hipStream_t stream) {
    const float* x     = (const float*)d_in[0];
    const float* ea    = (const float*)d_in[1];
    const float* xseq  = (const float*)d_in[2];
    const float* linW  = (const float*)d_in[3];
    const float* linB  = (const float*)d_in[4];
    const float* mW1   = (const float*)d_in[5];
    const float* mb1   = (const float*)d_in[6];
    const float* mW2   = (const float*)d_in[7];
    const float* mb2   = (const float*)d_in[8];
    const float* eps   = (const float*)d_in[9];
    const float* lnS   = (const float*)d_in[10];
    const float* lnB   = (const float*)d_in[11];
    const float* Wih   = (const float*)d_in[12];
    const float* Whh   = (const float*)d_in[13];
    const float* bih   = (const float*)d_in[14];
    const float* bhh   = (const float*)d_in[15];
    const float* llnS  = (const float*)d_in[16];
    const float* llnB  = (const float*)d_in[17];
    const float* fcW   = (const float*)d_in[18];
    const float* fcb   = (const float*)d_in[19];
    const int*   eidx  = (const int*)d_in[20];
    const int*   nidx  = (const int*)d_in[21];
    float* out = (float*)d_out;

    const int* srcs = eidx;
    const int* dsts = eidx + NE;

    // workspace layout
    float* ws   = (float*)d_ws;
    float* agg  = ws;                              // NN*64
    float* h1   = agg  + (size_t)NN * HID;
    float* h2   = h1   + (size_t)NN * HID;
    float* selp = h2   + (size_t)NN * HID;         // BB*G4
    float* W2T  = selp + (size_t)BB * G4;          // 32*G4
    float* xp   = W2T  + (size_t)32 * G4;          // TT*BB*G4
    int*   deg    = (int*)(xp + (size_t)TT * BB * G4);  // NN
    int*   rowptr = deg + NN;                      // NN+1 (+1 pad)
    int*   head   = rowptr + NN + 2;               // NN
    int2*  sorted = (int2*)(head + NN);            // NE (8B aligned)

    // ---- CSR build (shared by both layers) ----
    hipMemsetAsync(deg, 0, (size_t)NN * sizeof(int), stream);
    hist_kernel<<<(NE + 255) / 256, 256, 0, stream>>>(dsts, deg);
    scan_kernel<<<1, 1024, 0, stream>>>(deg, rowptr, head);
    scatter_kernel<<<(NE + 255) / 256, 256, 0, stream>>>(srcs, dsts, head, sorted);

    // ---- layer 0 ----
    edge_agg_kernel<<<2048, 256, 0, stream>>>(x, ea, linW, linB, rowptr, sorted, agg);
    node_kernel<<<512, 256, 0, stream>>>(x, agg, mW1, mb1, mW2, mb2, eps, lnS, lnB, h1);
    // ---- layer 1 ----
    edge_agg_kernel<<<2048, 256, 0, stream>>>(h1, ea, linW + 64*64, linB + 64, rowptr, sorted, agg);
    node_kernel<<<512, 256, 0, stream>>>(h1, agg, mW1 + 64*64, mb1 + 64, mW2 + 64*64, mb2 + 64,
                                         eps + 1, lnS + 64, lnB + 64, h2);
    // ---- LSTM input projection ----
    prep_kernel<<<BB + 1, 512, 0, stream>>>(Wih, bih, h2, nidx, W2T, selp);
    xp_kernel<<<TT * BB, 512, 0, stream>>>(xseq, selp, W2T, xp);
    // ---- LSTM recurrence + head ----
    lstm_kernel<<<BB, 512, 0, stream>>>(xp, Whh, bhh, llnS, llnB, fcW, fcb, out);
}

// Round 4
// 678.182 us; speedup vs baseline: 1.6318x; 1.6318x over previous
//
#include <hip/hip_runtime.h>
#include <cmath>

static constexpr int NN  = 50000;   // nodes
static constexpr int NE  = 800000;  // edges
static constexpr int HID = 64;
static constexpr int BB  = 64;      // batch
static constexpr int TT  = 200;     // seq len
static constexpr int LH  = 128;     // lstm hidden
static constexpr int G4  = 512;     // 4*LH

static constexpr int SCB = 125;     // scan blocks
static constexpr int SCH = 400;     // elems per scan block (125*400 = 50000)

typedef _Float16 h2 __attribute__((ext_vector_type(2)));

#ifndef __has_builtin
#define __has_builtin(x) 0
#endif
#if __has_builtin(__builtin_amdgcn_fdot2)
__device__ __forceinline__ float fdot2_(h2 a, h2 b, float c) {
    return __builtin_amdgcn_fdot2(a, b, c, false);
}
#else
__device__ __forceinline__ float fdot2_(h2 a, h2 b, float c) {
    return c + (float)a.x * (float)b.x + (float)a.y * (float)b.y;
}
#endif

__device__ __forceinline__ h2 as_h2(unsigned int u) {
    union { unsigned int u; h2 h; } cv; cv.u = u; return cv.h;
}

__device__ __forceinline__ float sigmoid_fast(float x) {
    return __fdividef(1.f, 1.f + __expf(-x));
}
__device__ __forceinline__ float tanh_fast(float x) {
    return __fdividef(2.f, 1.f + __expf(-2.f * x)) - 1.f;
}

// ================= CSR build =================
__global__ __launch_bounds__(256) void hist_kernel(const int* __restrict__ dsts,
                                                   int* __restrict__ deg) {
    int i = blockIdx.x * 256 + threadIdx.x;
    if (i < NE) atomicAdd(&deg[dsts[i]], 1);
}

// pass 1: per-block exclusive scan (local) + block sums
__global__ __launch_bounds__(512) void scan1_kernel(const int* __restrict__ deg,
                                                    int* __restrict__ loc,
                                                    int* __restrict__ bsum) {
    __shared__ int ws[8];
    const int b = blockIdx.x, t = threadIdx.x;
    const int idx = b * SCH + t;
    const int lane = t & 63, wv = t >> 6;
    int v = (t < SCH && idx < NN) ? deg[idx] : 0;
    int x = v;
    #pragma unroll
    for (int off = 1; off < 64; off <<= 1) {
        int y = __shfl_up(x, off);
        if (lane >= off) x += y;
    }
    if (lane == 63) ws[wv] = x;
    __syncthreads();
    if (t < 8) {
        int s = ws[t];
        #pragma unroll
        for (int off = 1; off < 8; off <<= 1) {
            int y = __shfl_up(s, off);
            if (t >= off) s += y;
        }
        ws[t] = s;
    }
    __syncthreads();
    const int base = wv ? ws[wv - 1] : 0;
    if (t < SCH && idx < NN) loc[idx] = base + x - v;
    if (t == 511) bsum[b] = ws[7];
}

// pass 2: scan the 125 block sums (single thread — tiny)
__global__ void scan2_kernel(const int* __restrict__ bsum,
                             int* __restrict__ boff,
                             int* __restrict__ rowptr) {
    int tot = 0;
    for (int i = 0; i < SCB; ++i) { boff[i] = tot; tot += bsum[i]; }
    rowptr[NN] = tot;
}

// pass 3: add block offsets, write rowptr + head
__global__ __launch_bounds__(512) void scan3_kernel(const int* __restrict__ loc,
                                                    const int* __restrict__ boff,
                                                    int* __restrict__ rowptr,
                                                    int* __restrict__ head) {
    const int b = blockIdx.x, t = threadIdx.x;
    const int idx = b * SCH + t;
    if (t < SCH && idx < NN) {
        int r = loc[idx] + boff[b];
        rowptr[idx] = r;
        head[idx] = r;
    }
}

__global__ __launch_bounds__(256) void scatter_kernel(const int* __restrict__ srcs,
                                                      const int* __restrict__ dsts,
                                                      int* __restrict__ head,
                                                      int* __restrict__ perm,
                                                      int* __restrict__ ssrc) {
    int e = blockIdx.x * 256 + threadIdx.x;
    if (e < NE) {
        int d = dsts[e];
        int pos = atomicAdd(&head[d], 1);
        perm[e] = pos;
        ssrc[pos] = srcs[e];
    }
}

// permute edge_attr into dst-sorted order, fp32 -> fp16 (one-time, shared by both layers)
__global__ __launch_bounds__(256) void permute_kernel(const float* __restrict__ ea,
                                                      const int* __restrict__ perm,
                                                      ushort4* __restrict__ easort) {
    const int lane = threadIdx.x & 63, wid = threadIdx.x >> 6;
    const int slot = lane >> 4, hw = lane & 15;
    const int e = (blockIdx.x * 4 + wid) * 4 + slot;
    if (e < NE) {
        const int p = perm[e];
        float4 v = ((const float4*)ea)[(size_t)e * 16 + hw];
        union { _Float16 h[4]; ushort4 u; } pk;
        pk.h[0] = (_Float16)v.x; pk.h[1] = (_Float16)v.y;
        pk.h[2] = (_Float16)v.z; pk.h[3] = (_Float16)v.w;
        easort[(size_t)p * 16 + hw] = pk.u;
    }
}

// ========= fused edge pass: CSR by dst, coalesced fp16 reads, fdot2, no atomics =========
// one wave per node: agg[n] = sum_{e in in(n)} relu(EA[e]@W^T + b + h[src(e)])
__global__ __launch_bounds__(256) void edge_agg_kernel(
    const float*   __restrict__ h_in,
    const ushort4* __restrict__ easort,  // [NE][16] (64 halfs per edge, dst-sorted)
    const float*   __restrict__ W,       // [64][64] W[c][k]
    const float*   __restrict__ bias,    // [64]
    const int*     __restrict__ rowptr,
    const int*     __restrict__ ssrc,    // src per sorted pos
    float*         __restrict__ agg)
{
    __shared__ ushort4 stage[4][64];     // per wave: 4 edges x 64 halfs
    const int lane = threadIdx.x & 63;
    const int wid  = threadIdx.x >> 6;
    const int slot = lane >> 4, hw = lane & 15;

    // weight row 'lane' packed to half2 (16 VGPRs)
    h2 w2[32];
    {
        const float4* wf = (const float4*)(W + lane * 64);
        #pragma unroll
        for (int k4 = 0; k4 < 16; ++k4) {
            float4 v = wf[k4];
            h2 a; a.x = (_Float16)v.x; a.y = (_Float16)v.y;
            h2 b; b.x = (_Float16)v.z; b.y = (_Float16)v.w;
            w2[2*k4] = a; w2[2*k4+1] = b;
        }
    }
    const float bc = bias[lane];

    const int gw = blockIdx.x * 4 + wid;
    const int nw = gridDim.x * 4;
    for (int n = gw; n < NN; n += nw) {
        const int ofs = rowptr[n];
        const int dg  = rowptr[n + 1] - ofs;
        float acc = 0.f;
        for (int c = 0; c < dg; c += 4) {
            const int rem = dg - c;
            const int pick = slot < rem ? slot : rem - 1;
            const int ssv = ssrc[ofs + c + pick];
            stage[wid][lane] = easort[(size_t)(ofs + c + pick) * 16 + hw];
            if (rem >= 4) {
                float hv[4];
                #pragma unroll
                for (int j = 0; j < 4; ++j) {
                    int sj = __shfl(ssv, j << 4);
                    hv[j] = h_in[(size_t)sj * HID + lane];
                }
                asm volatile("s_waitcnt lgkmcnt(0)" ::: "memory");
                #pragma unroll
                for (int j = 0; j < 4; ++j) {
                    const uint4* stu = (const uint4*)&stage[wid][j * 16];
                    float aE = bc;
                    #pragma unroll
                    for (int k = 0; k < 8; ++k) {
                        uint4 u = stu[k];
                        aE = fdot2_(as_h2(u.x), w2[4*k+0], aE);
                        aE = fdot2_(as_h2(u.y), w2[4*k+1], aE);
                        aE = fdot2_(as_h2(u.z), w2[4*k+2], aE);
                        aE = fdot2_(as_h2(u.w), w2[4*k+3], aE);
                    }
                    float m = aE + hv[j];
                    acc += m > 0.f ? m : 0.f;
                }
            } else {
                asm volatile("s_waitcnt lgkmcnt(0)" ::: "memory");
                for (int j = 0; j < rem; ++j) {
                    int sj = __shfl(ssv, j << 4);
                    const uint4* stu = (const uint4*)&stage[wid][j * 16];
                    float aE = bc;
                    #pragma unroll
                    for (int k = 0; k < 8; ++k) {
                        uint4 u = stu[k];
                        aE = fdot2_(as_h2(u.x), w2[4*k+0], aE);
                        aE = fdot2_(as_h2(u.y), w2[4*k+1], aE);
                        aE = fdot2_(as_h2(u.z), w2[4*k+2], aE);
                        aE = fdot2_(as_h2(u.w), w2[4*k+3], aE);
                    }
                    float m = aE + h_in[(size_t)sj * HID + lane];
                    acc += m > 0.f ? m : 0.f;
                }
            }
        }
        agg[(size_t)n * HID + lane] = acc;
    }
}

// ---------------- node pass ----------------
__global__ __launch_bounds__(256) void node_kernel(
    const float* __restrict__ h_in,
    const float* __restrict__ agg,
    const float* __restrict__ W1, const float* __restrict__ b1,
    const float* __restrict__ W2, const float* __restrict__ b2,
    const float* __restrict__ epsp,
    const float* __restrict__ lnS, const float* __restrict__ lnB,
    float*       __restrict__ h_out)
{
    __shared__ float zbuf[4][64];
    __shared__ float tbuf[4][64];
    const int lane = threadIdx.x & 63;
    const int wid  = threadIdx.x >> 6;

    float w1[64], w2[64];
    {
        const float4* wf1 = (const float4*)(W1 + lane * 64);
        const float4* wf2 = (const float4*)(W2 + lane * 64);
        #pragma unroll
        for (int k4 = 0; k4 < 16; ++k4) {
            float4 a = wf1[k4], b = wf2[k4];
            w1[4*k4+0]=a.x; w1[4*k4+1]=a.y; w1[4*k4+2]=a.z; w1[4*k4+3]=a.w;
            w2[4*k4+0]=b.x; w2[4*k4+1]=b.y; w2[4*k4+2]=b.z; w2[4*k4+3]=b.w;
        }
    }
    const float b1c = b1[lane], b2c = b2[lane];
    const float sC = lnS[lane], bC = lnB[lane];
    const float epv = 1.f + epsp[0];

    const int gw = blockIdx.x * 4 + wid;
    const int nw = gridDim.x * 4;
    for (int n = gw; n < NN; n += nw) {
        float z = epv * h_in[(size_t)n*HID + lane] + agg[(size_t)n*HID + lane];
        zbuf[wid][lane] = z;
        asm volatile("s_waitcnt lgkmcnt(0)" ::: "memory");
        float acc = b1c;
        {
            const float4* zf = (const float4*)&zbuf[wid][0];
            #pragma unroll
            for (int k4 = 0; k4 < 16; ++k4) {
                float4 v = zf[k4];
                acc = fmaf(v.x, w1[4*k4+0], acc);
                acc = fmaf(v.y, w1[4*k4+1], acc);
                acc = fmaf(v.z, w1[4*k4+2], acc);
                acc = fmaf(v.w, w1[4*k4+3], acc);
            }
        }
        acc = acc > 0.f ? acc : 0.f;
        tbuf[wid][lane] = acc;
        asm volatile("s_waitcnt lgkmcnt(0)" ::: "memory");
        float acc2 = b2c;
        {
            const float4* tf = (const float4*)&tbuf[wid][0];
            #pragma unroll
            for (int k4 = 0; k4 < 16; ++k4) {
                float4 v = tf[k4];
                acc2 = fmaf(v.x, w2[4*k4+0], acc2);
                acc2 = fmaf(v.y, w2[4*k4+1], acc2);
                acc2 = fmaf(v.z, w2[4*k4+2], acc2);
                acc2 = fmaf(v.w, w2[4*k4+3], acc2);
            }
        }
        float s1 = acc2, s2 = acc2 * acc2;
        #pragma unroll
        for (int off = 32; off >= 1; off >>= 1) {
            s1 += __shfl_xor(s1, off);
            s2 += __shfl_xor(s2, off);
        }
        float mu  = s1 * (1.f/64.f);
        float var = s2 * (1.f/64.f) - mu * mu;
        float r   = rsqrtf(var + 1e-5f);
        float o   = (acc2 - mu) * r * sC + bC;
        h_out[(size_t)n*HID + lane] = o > 0.f ? o : 0.f;
    }
}

// ---------------- prep: W2T transpose + selp = b_ih + sel @ W_ih[:, :64]^T ----------------
__global__ __launch_bounds__(512) void prep_kernel(
    const float* __restrict__ Wih,   // [512][96]
    const float* __restrict__ bih,   // [512]
    const float* __restrict__ h2v,   // [NN][64]
    const int*   __restrict__ nidx,  // [64]
    float*       __restrict__ W2T,   // [32][512]
    float*       __restrict__ selp)  // [64][512]
{
    const int g = threadIdx.x;
    if (blockIdx.x == BB) {
        #pragma unroll
        for (int k = 0; k < 32; ++k)
            W2T[k * G4 + g] = Wih[g * 96 + 64 + k];
    } else {
        const int b = blockIdx.x;
        __shared__ float hrow[64];
        if (g < 64) hrow[g] = h2v[(size_t)nidx[b] * HID + g];
        __syncthreads();
        float acc = bih[g];
        #pragma unroll
        for (int k = 0; k < 64; ++k)
            acc = fmaf(hrow[k], Wih[g * 96 + k], acc);
        selp[b * G4 + g] = acc;
    }
}

// ---------------- xp[t][b][g] = selp[b][g] + x_seq[b][t] @ W2T[:,g] ----------------
__global__ __launch_bounds__(512) void xp_kernel(
    const float* __restrict__ xseq,  // [B][T][32]
    const float* __restrict__ selp,  // [B][512]
    const float* __restrict__ W2T,   // [32][512]
    float*       __restrict__ xp)    // [T][B][512]
{
    const int g   = threadIdx.x;
    const int row = blockIdx.x;      // row = t*64 + b
    const int t   = row >> 6;
    const int b   = row & 63;
    __shared__ float xs[32];
    if (g < 32) xs[g] = xseq[((size_t)b * TT + t) * 32 + g];
    __syncthreads();
    float acc = selp[b * G4 + g];
    #pragma unroll
    for (int k = 0; k < 32; ++k)
        acc = fmaf(xs[k], W2T[k * G4 + g], acc);
    xp[(size_t)row * G4 + g] = acc;
}

// ---------------- LSTM recurrence + final LN + fc ----------------
__global__ __launch_bounds__(512) void lstm_kernel(
    const float* __restrict__ xp,    // [T][B][512]
    const float* __restrict__ Whh,   // [512][128]
    const float* __restrict__ bhh,   // [512]
    const float* __restrict__ lnS, const float* __restrict__ lnB,  // [128]
    const float* __restrict__ fcW,   // [1][128]
    const float* __restrict__ fcb,   // [1]
    float*       __restrict__ out)   // [64]
{
    const int g = threadIdx.x;   // gate index 0..511
    const int b = blockIdx.x;    // batch row
    const int j = g & 127;       // hidden unit for elementwise phase
    const int gt = g >> 7;       // gate type (wave-uniform)

    float w[128];
    {
        const float4* wf = (const float4*)(Whh + (size_t)g * LH);
        #pragma unroll
        for (int k4 = 0; k4 < 32; ++k4) {
            float4 v = wf[k4];
            w[4*k4+0]=v.x; w[4*k4+1]=v.y; w[4*k4+2]=v.z; w[4*k4+3]=v.w;
        }
    }
    const float bg = bhh[g];

    __shared__ float h_lds[LH];
    __shared__ float gates[G4];
    if (g < LH) h_lds[g] = 0.f;
    float c = 0.f;
    __syncthreads();

    float xv = xp[(size_t)b * G4 + g];   // t=0 slice

    for (int t = 0; t < TT; ++t) {
        const int tn = (t + 1 < TT) ? t + 1 : t;
        const float xv_next = xp[((size_t)tn * BB + b) * G4 + g];

        float a0 = 0.f, a1 = 0.f, a2 = 0.f, a3 = 0.f;
        const float4* h4 = (const float4*)h_lds;
        #pragma unroll
        for (int k4 = 0; k4 < 32; k4 += 4) {
            float4 v0 = h4[k4+0], v1 = h4[k4+1], v2 = h4[k4+2], v3 = h4[k4+3];
            a0 = fmaf(v0.x, w[4*k4+ 0], a0); a0 = fmaf(v0.y, w[4*k4+ 1], a0);
            a0 = fmaf(v0.z, w[4*k4+ 2], a0); a0 = fmaf(v0.w, w[4*k4+ 3], a0);
            a1 = fmaf(v1.x, w[4*k4+ 4], a1); a1 = fmaf(v1.y, w[4*k4+ 5], a1);
            a1 = fmaf(v1.z, w[4*k4+ 6], a1); a1 = fmaf(v1.w, w[4*k4+ 7], a1);
            a2 = fmaf(v2.x, w[4*k4+ 8], a2); a2 = fmaf(v2.y, w[4*k4+ 9], a2);
            a2 = fmaf(v2.z, w[4*k4+10], a2); a2 = fmaf(v2.w, w[4*k4+11], a2);
            a3 = fmaf(v3.x, w[4*k4+12], a3); a3 = fmaf(v3.y, w[4*k4+13], a3);
            a3 = fmaf(v3.z, w[4*k4+14], a3); a3 = fmaf(v3.w, w[4*k4+15], a3);
        }
        float acc = xv + bg + ((a0 + a1) + (a2 + a3));

        float act = (gt == 2) ? tanh_fast(acc) : sigmoid_fast(acc);
        gates[g] = act;
        __syncthreads();

        float iv = gates[j];
        float fv = gates[j + LH];
        float gv = gates[j + 2*LH];
        float ov = gates[j + 3*LH];
        c = fmaf(fv, c, iv * gv);
        float hv = ov * tanh_fast(c);
        if (g < LH) h_lds[j] = hv;
        __syncthreads();

        xv = xv_next;
    }

    if (g < 64) {
        float h0 = h_lds[g], h1 = h_lds[g + 64];
        float s1 = h0 + h1, s2 = h0*h0 + h1*h1;
        #pragma unroll
        for (int off = 32; off >= 1; off >>= 1) {
            s1 += __shfl_xor(s1, off);
            s2 += __shfl_xor(s2, off);
        }
        float mu  = s1 * (1.f/128.f);
        float var = s2 * (1.f/128.f) - mu * mu;
        float r   = rsqrtf(var + 1e-5f);
        float p = ((h0 - mu)*r*lnS[g]      + lnB[g])      * fcW[g]
                + ((h1 - mu)*r*lnS[g + 64] + lnB[g + 64]) * fcW[g + 64];
        #pragma unroll
        for (int off = 32; off >= 1; off >>= 1) p += __shfl_xor(p, off);
        if (g == 0) out[b] = p + fcb[0];
    }
}

extern "C" void kernel_launch(void* const* d_in, const int* in_sizes, int n_in,
                              void* d_out, int out_size, void* d_ws, size_t ws_size,
                              hipStream_t stream) {
    const float* x     = (const float*)d_in[0];
    const float* ea    = (const float*)d_in[1];
    const float* xseq  = (const float*)d_in[2];
    const float* linW  = (const float*)d_in[3];
    const float* linB  = (const float*)d_in[4];
    const float* mW1   = (const float*)d_in[5];
    const float* mb1   = (const float*)d_in[6];
    const float* mW2   = (const float*)d_in[7];
    const float* mb2   = (const float*)d_in[8];
    const float* eps   = (const float*)d_in[9];
    const float* lnS   = (const float*)d_in[10];
    const float* lnB   = (const float*)d_in[11];
    const float* Wih   = (const float*)d_in[12];
    const float* Whh   = (const float*)d_in[13];
    const float* bih   = (const float*)d_in[14];
    const float* bhh   = (const float*)d_in[15];
    const float* llnS  = (const float*)d_in[16];
    const float* llnB  = (const float*)d_in[17];
    const float* fcW   = (const float*)d_in[18];
    const float* fcb   = (const float*)d_in[19];
    const int*   eidx  = (const int*)d_in[20];
    const int*   nidx  = (const int*)d_in[21];
    float* out = (float*)d_out;

    const int* srcs = eidx;
    const int* dsts = eidx + NE;

    // workspace layout
    float* ws   = (float*)d_ws;
    float* agg  = ws;                              // NN*64
    float* h1   = agg  + (size_t)NN * HID;
    float* h2   = h1   + (size_t)NN * HID;
    float* selp = h2   + (size_t)NN * HID;         // BB*G4
    float* W2T  = selp + (size_t)BB * G4;          // 32*G4
    float* xp   = W2T  + (size_t)32 * G4;          // TT*BB*G4
    int*   deg    = (int*)(xp + (size_t)TT * BB * G4);  // NN
    int*   rowptr = deg + NN;                      // NN+1
    int*   head   = rowptr + NN + 2;               // NN
    int*   loc    = head + NN;                     // NN
    int*   bsum   = loc + NN;                      // SCB
    int*   boff   = bsum + SCB + 3;                // SCB
    int*   perm   = boff + SCB + 3;                // NE
    int*   ssrc   = perm + NE;                     // NE
    // fp16 sorted edge features, 16B aligned
    uintptr_t ep = (uintptr_t)(ssrc + NE);
    ep = (ep + 15) & ~(uintptr_t)15;
    ushort4* easort = (ushort4*)ep;                // NE*16 ushort4 = 102.4 MB

    // ---- CSR build + ea permute (shared by both layers) ----
    hipMemsetAsync(deg, 0, (size_t)NN * sizeof(int), stream);
    hist_kernel<<<(NE + 255) / 256, 256, 0, stream>>>(dsts, deg);
    scan1_kernel<<<SCB, 512, 0, stream>>>(deg, loc, bsum);
    scan2_kernel<<<1, 1, 0, stream>>>(bsum, boff, rowptr);
    scan3_kernel<<<SCB, 512, 0, stream>>>(loc, boff, rowptr, head);
    scatter_kernel<<<(NE + 255) / 256, 256, 0, stream>>>(srcs, dsts, head, perm, ssrc);
    permute_kernel<<<NE / 16, 256, 0, stream>>>(ea, perm, easort);

    // ---- layer 0 ----
    edge_agg_kernel<<<2048, 256, 0, stream>>>(x, easort, linW, linB, rowptr, ssrc, agg);
    node_kernel<<<512, 256, 0, stream>>>(x, agg, mW1, mb1, mW2, mb2, eps, lnS, lnB, h1);
    // ---- layer 1 ----
    edge_agg_kernel<<<2048, 256, 0, stream>>>(h1, easort, linW + 64*64, linB + 64, rowptr, ssrc, agg);
    node_kernel<<<512, 256, 0, stream>>>(h1, agg, mW1 + 64*64, mb1 + 64, mW2 + 64*64, mb2 + 64,
                                         eps + 1, lnS + 64, lnB + 64, h2);
    // ---- LSTM input projection ----
    prep_kernel<<<BB + 1, 512, 0, stream>>>(Wih, bih, h2, nidx, W2T, selp);
    xp_kernel<<<TT * BB, 512, 0, stream>>>(xseq, selp, W2T, xp);
    // ---- LSTM recurrence + head ----
    lstm_kernel<<<BB, 512, 0, stream>>>(xp, Whh, bhh, llnS, llnB, fcW, fcb, out);
}

// Round 5
// 665.602 us; speedup vs baseline: 1.6626x; 1.0189x over previous
//
#include <hip/hip_runtime.h>
#include <cmath>

static constexpr int NN  = 50000;   // nodes
static constexpr int NE  = 800000;  // edges
static constexpr int HID = 64;
static constexpr int BB  = 64;      // batch
static constexpr int TT  = 200;     // seq len
static constexpr int LH  = 128;     // lstm hidden
static constexpr int G4  = 512;     // 4*LH

static constexpr int SCB = 125;     // scan blocks
static constexpr int SCH = 400;     // elems per scan block (125*400 = 50000)

typedef _Float16 h2 __attribute__((ext_vector_type(2)));

#ifndef __has_builtin
#define __has_builtin(x) 0
#endif
#if __has_builtin(__builtin_amdgcn_fdot2)
__device__ __forceinline__ float fdot2_(h2 a, h2 b, float c) {
    return __builtin_amdgcn_fdot2(a, b, c, false);
}
#else
__device__ __forceinline__ float fdot2_(h2 a, h2 b, float c) {
    return c + (float)a.x * (float)b.x + (float)a.y * (float)b.y;
}
#endif

__device__ __forceinline__ h2 as_h2(unsigned int u) {
    union { unsigned int u; h2 h; } cv; cv.u = u; return cv.h;
}
__device__ __forceinline__ unsigned int as_u32(h2 h) {
    union { h2 h; unsigned int u; } cv; cv.h = h; return cv.u;
}

__device__ __forceinline__ float sigmoid_fast(float x) {
    return __fdividef(1.f, 1.f + __expf(-x));
}
__device__ __forceinline__ float tanh_fast(float x) {
    return __fdividef(2.f, 1.f + __expf(-2.f * x)) - 1.f;
}

// ================= CSR build =================
__global__ __launch_bounds__(256) void hist_kernel(const int* __restrict__ dsts,
                                                   int* __restrict__ deg) {
    int i = blockIdx.x * 256 + threadIdx.x;
    if (i < NE) atomicAdd(&deg[dsts[i]], 1);
}

// pass 1: per-block exclusive scan (local) + block sums
__global__ __launch_bounds__(512) void scan1_kernel(const int* __restrict__ deg,
                                                    int* __restrict__ loc,
                                                    int* __restrict__ bsum) {
    __shared__ int ws[8];
    const int b = blockIdx.x, t = threadIdx.x;
    const int idx = b * SCH + t;
    const int lane = t & 63, wv = t >> 6;
    int v = (t < SCH && idx < NN) ? deg[idx] : 0;
    int x = v;
    #pragma unroll
    for (int off = 1; off < 64; off <<= 1) {
        int y = __shfl_up(x, off);
        if (lane >= off) x += y;
    }
    if (lane == 63) ws[wv] = x;
    __syncthreads();
    if (t < 8) {
        int s = ws[t];
        #pragma unroll
        for (int off = 1; off < 8; off <<= 1) {
            int y = __shfl_up(s, off);
            if (t >= off) s += y;
        }
        ws[t] = s;
    }
    __syncthreads();
    const int base = wv ? ws[wv - 1] : 0;
    if (t < SCH && idx < NN) loc[idx] = base + x - v;
    if (t == 511) bsum[b] = ws[7];
}

// pass 2: scan the 125 block sums (single thread — tiny)
__global__ void scan2_kernel(const int* __restrict__ bsum,
                             int* __restrict__ boff,
                             int* __restrict__ rowptr) {
    int tot = 0;
    for (int i = 0; i < SCB; ++i) { boff[i] = tot; tot += bsum[i]; }
    rowptr[NN] = tot;
}

// pass 3: add block offsets, write rowptr + head
__global__ __launch_bounds__(512) void scan3_kernel(const int* __restrict__ loc,
                                                    const int* __restrict__ boff,
                                                    int* __restrict__ rowptr,
                                                    int* __restrict__ head) {
    const int b = blockIdx.x, t = threadIdx.x;
    const int idx = b * SCH + t;
    if (t < SCH && idx < NN) {
        int r = loc[idx] + boff[b];
        rowptr[idx] = r;
        head[idx] = r;
    }
}

__global__ __launch_bounds__(256) void scatter_kernel(const int* __restrict__ srcs,
                                                      const int* __restrict__ dsts,
                                                      int* __restrict__ head,
                                                      int* __restrict__ perm,
                                                      int* __restrict__ ssrc) {
    int e = blockIdx.x * 256 + threadIdx.x;
    if (e < NE) {
        int d = dsts[e];
        int pos = atomicAdd(&head[d], 1);
        perm[e] = pos;
        ssrc[pos] = srcs[e];
    }
}

// permute edge_attr into dst-sorted order, fp32 -> fp16 (one-time, shared by both layers)
__global__ __launch_bounds__(256) void permute_kernel(const float* __restrict__ ea,
                                                      const int* __restrict__ perm,
                                                      ushort4* __restrict__ easort) {
    const int lane = threadIdx.x & 63, wid = threadIdx.x >> 6;
    const int slot = lane >> 4, hw = lane & 15;
    const int e = (blockIdx.x * 4 + wid) * 4 + slot;
    if (e < NE) {
        const int p = perm[e];
        float4 v = ((const float4*)ea)[(size_t)e * 16 + hw];
        union { _Float16 h[4]; ushort4 u; } pk;
        pk.h[0] = (_Float16)v.x; pk.h[1] = (_Float16)v.y;
        pk.h[2] = (_Float16)v.z; pk.h[3] = (_Float16)v.w;
        easort[(size_t)p * 16 + hw] = pk.u;
    }
}

// ========= fused edge pass: CSR by dst, coalesced fp16 reads, fdot2, no atomics =========
__global__ __launch_bounds__(256) void edge_agg_kernel(
    const float*   __restrict__ h_in,
    const ushort4* __restrict__ easort,  // [NE][16] (64 halfs per edge, dst-sorted)
    const float*   __restrict__ W,       // [64][64] W[c][k]
    const float*   __restrict__ bias,    // [64]
    const int*     __restrict__ rowptr,
    const int*     __restrict__ ssrc,    // src per sorted pos
    float*         __restrict__ agg)
{
    __shared__ ushort4 stage[4][64];     // per wave: 4 edges x 64 halfs
    const int lane = threadIdx.x & 63;
    const int wid  = threadIdx.x >> 6;
    const int slot = lane >> 4, hw = lane & 15;

    // weight row 'lane' packed to half2 (16 VGPRs)
    h2 w2[32];
    {
        const float4* wf = (const float4*)(W + lane * 64);
        #pragma unroll
        for (int k4 = 0; k4 < 16; ++k4) {
            float4 v = wf[k4];
            h2 a; a.x = (_Float16)v.x; a.y = (_Float16)v.y;
            h2 b; b.x = (_Float16)v.z; b.y = (_Float16)v.w;
            w2[2*k4] = a; w2[2*k4+1] = b;
        }
    }
    const float bc = bias[lane];

    const int gw = blockIdx.x * 4 + wid;
    const int nw = gridDim.x * 4;
    for (int n = gw; n < NN; n += nw) {
        const int ofs = rowptr[n];
        const int dg  = rowptr[n + 1] - ofs;
        float acc = 0.f;
        for (int c = 0; c < dg; c += 4) {
            const int rem = dg - c;
            const int pick = slot < rem ? slot : rem - 1;
            const int ssv = ssrc[ofs + c + pick];
            stage[wid][lane] = easort[(size_t)(ofs + c + pick) * 16 + hw];
            if (rem >= 4) {
                float hv[4];
                #pragma unroll
                for (int j = 0; j < 4; ++j) {
                    int sj = __shfl(ssv, j << 4);
                    hv[j] = h_in[(size_t)sj * HID + lane];
                }
                asm volatile("s_waitcnt lgkmcnt(0)" ::: "memory");
                #pragma unroll
                for (int j = 0; j < 4; ++j) {
                    const uint4* stu = (const uint4*)&stage[wid][j * 16];
                    float aE = bc;
                    #pragma unroll
                    for (int k = 0; k < 8; ++k) {
                        uint4 u = stu[k];
                        aE = fdot2_(as_h2(u.x), w2[4*k+0], aE);
                        aE = fdot2_(as_h2(u.y), w2[4*k+1], aE);
                        aE = fdot2_(as_h2(u.z), w2[4*k+2], aE);
                        aE = fdot2_(as_h2(u.w), w2[4*k+3], aE);
                    }
                    float m = aE + hv[j];
                    acc += m > 0.f ? m : 0.f;
                }
            } else {
                asm volatile("s_waitcnt lgkmcnt(0)" ::: "memory");
                for (int j = 0; j < rem; ++j) {
                    int sj = __shfl(ssv, j << 4);
                    const uint4* stu = (const uint4*)&stage[wid][j * 16];
                    float aE = bc;
                    #pragma unroll
                    for (int k = 0; k < 8; ++k) {
                        uint4 u = stu[k];
                        aE = fdot2_(as_h2(u.x), w2[4*k+0], aE);
                        aE = fdot2_(as_h2(u.y), w2[4*k+1], aE);
                        aE = fdot2_(as_h2(u.z), w2[4*k+2], aE);
                        aE = fdot2_(as_h2(u.w), w2[4*k+3], aE);
                    }
                    float m = aE + h_in[(size_t)sj * HID + lane];
                    acc += m > 0.f ? m : 0.f;
                }
            }
        }
        agg[(size_t)n * HID + lane] = acc;
    }
}

// ---------------- node pass ----------------
__global__ __launch_bounds__(256) void node_kernel(
    const float* __restrict__ h_in,
    const float* __restrict__ agg,
    const float* __restrict__ W1, const float* __restrict__ b1,
    const float* __restrict__ W2, const float* __restrict__ b2,
    const float* __restrict__ epsp,
    const float* __restrict__ lnS, const float* __restrict__ lnB,
    float*       __restrict__ h_out)
{
    __shared__ float zbuf[4][64];
    __shared__ float tbuf[4][64];
    const int lane = threadIdx.x & 63;
    const int wid  = threadIdx.x >> 6;

    float w1[64], w2[64];
    {
        const float4* wf1 = (const float4*)(W1 + lane * 64);
        const float4* wf2 = (const float4*)(W2 + lane * 64);
        #pragma unroll
        for (int k4 = 0; k4 < 16; ++k4) {
            float4 a = wf1[k4], b = wf2[k4];
            w1[4*k4+0]=a.x; w1[4*k4+1]=a.y; w1[4*k4+2]=a.z; w1[4*k4+3]=a.w;
            w2[4*k4+0]=b.x; w2[4*k4+1]=b.y; w2[4*k4+2]=b.z; w2[4*k4+3]=b.w;
        }
    }
    const float b1c = b1[lane], b2c = b2[lane];
    const float sC = lnS[lane], bC = lnB[lane];
    const float epv = 1.f + epsp[0];

    const int gw = blockIdx.x * 4 + wid;
    const int nw = gridDim.x * 4;
    for (int n = gw; n < NN; n += nw) {
        float z = epv * h_in[(size_t)n*HID + lane] + agg[(size_t)n*HID + lane];
        zbuf[wid][lane] = z;
        asm volatile("s_waitcnt lgkmcnt(0)" ::: "memory");
        float acc = b1c;
        {
            const float4* zf = (const float4*)&zbuf[wid][0];
            #pragma unroll
            for (int k4 = 0; k4 < 16; ++k4) {
                float4 v = zf[k4];
                acc = fmaf(v.x, w1[4*k4+0], acc);
                acc = fmaf(v.y, w1[4*k4+1], acc);
                acc = fmaf(v.z, w1[4*k4+2], acc);
                acc = fmaf(v.w, w1[4*k4+3], acc);
            }
        }
        acc = acc > 0.f ? acc : 0.f;
        tbuf[wid][lane] = acc;
        asm volatile("s_waitcnt lgkmcnt(0)" ::: "memory");
        float acc2 = b2c;
        {
            const float4* tf = (const float4*)&tbuf[wid][0];
            #pragma unroll
            for (int k4 = 0; k4 < 16; ++k4) {
                float4 v = tf[k4];
                acc2 = fmaf(v.x, w2[4*k4+0], acc2);
                acc2 = fmaf(v.y, w2[4*k4+1], acc2);
                acc2 = fmaf(v.z, w2[4*k4+2], acc2);
                acc2 = fmaf(v.w, w2[4*k4+3], acc2);
            }
        }
        float s1 = acc2, s2 = acc2 * acc2;
        #pragma unroll
        for (int off = 32; off >= 1; off >>= 1) {
            s1 += __shfl_xor(s1, off);
            s2 += __shfl_xor(s2, off);
        }
        float mu  = s1 * (1.f/64.f);
        float var = s2 * (1.f/64.f) - mu * mu;
        float r   = rsqrtf(var + 1e-5f);
        float o   = (acc2 - mu) * r * sC + bC;
        h_out[(size_t)n*HID + lane] = o > 0.f ? o : 0.f;
    }
}

// ---------------- prep: W2T transpose + selp = b_ih + sel @ W_ih[:, :64]^T ----------------
// outputs stored PERMUTED to lstm thread order: thread t <- gate (t&3)*128 + (t>>2)
__global__ __launch_bounds__(512) void prep_kernel(
    const float* __restrict__ Wih,   // [512][96]
    const float* __restrict__ bih,   // [512]
    const float* __restrict__ h2v,   // [NN][64]
    const int*   __restrict__ nidx,  // [64]
    float*       __restrict__ W2T,   // [32][512] permuted cols
    float*       __restrict__ selp)  // [64][512] permuted cols
{
    const int g = threadIdx.x;                        // gate index 0..511
    const int pos = ((g & 127) << 2) | (g >> 7);      // lstm thread owning gate g
    if (blockIdx.x == BB) {
        #pragma unroll
        for (int k = 0; k < 32; ++k)
            W2T[k * G4 + pos] = Wih[g * 96 + 64 + k];
    } else {
        const int b = blockIdx.x;
        __shared__ float hrow[64];
        if (g < 64) hrow[g] = h2v[(size_t)nidx[b] * HID + g];
        __syncthreads();
        float acc = bih[g];
        #pragma unroll
        for (int k = 0; k < 64; ++k)
            acc = fmaf(hrow[k], Wih[g * 96 + k], acc);
        selp[b * G4 + pos] = acc;
    }
}

// ---------------- xp[t][b][tid] = selp[b][tid] + x_seq[b][t] @ W2T[:,tid] (all permuted) ----------------
__global__ __launch_bounds__(512) void xp_kernel(
    const float* __restrict__ xseq,  // [B][T][32]
    const float* __restrict__ selp,  // [B][512] permuted
    const float* __restrict__ W2T,   // [32][512] permuted
    float*       __restrict__ xp)    // [T][B][512] permuted
{
    const int g   = threadIdx.x;
    const int row = blockIdx.x;      // row = t*64 + b
    const int t   = row >> 6;
    const int b   = row & 63;
    __shared__ float xs[32];
    if (g < 32) xs[g] = xseq[((size_t)b * TT + t) * 32 + g];
    __syncthreads();
    float acc = selp[b * G4 + g];
    #pragma unroll
    for (int k = 0; k < 32; ++k)
        acc = fmaf(xs[k], W2T[k * G4 + g], acc);
    xp[(size_t)row * G4 + g] = acc;
}

// ---------------- LSTM recurrence + final LN + fc ----------------
// thread t: gate type gt=t&3 (0=i 1=f 2=g 3=o), hidden unit j=t>>2.
// gates exchanged in-wave via shfl_xor; c replicated x4; ONE barrier/step
// (double-buffered packed-fp16 h); Whh fp16-packed in 64 VGPRs, dot2 inner loop.
__global__ __launch_bounds__(512) void lstm_kernel(
    const float* __restrict__ xp,    // [T][B][512] thread-order
    const float* __restrict__ Whh,   // [512][128]
    const float* __restrict__ bhh,   // [512]
    const float* __restrict__ lnS, const float* __restrict__ lnB,  // [128]
    const float* __restrict__ fcW,   // [1][128]
    const float* __restrict__ fcb,   // [1]
    float*       __restrict__ out)   // [64]
{
    const int t  = threadIdx.x;
    const int b  = blockIdx.x;
    const int gt = t & 3;
    const int j  = t >> 2;
    const int gate = gt * LH + j;    // original gate row

    // Whh row 'gate' packed fp16 -> 64 VGPRs
    h2 w2[64];
    {
        const float4* wf = (const float4*)(Whh + (size_t)gate * LH);
        #pragma unroll
        for (int k4 = 0; k4 < 32; ++k4) {
            float4 v = wf[k4];
            h2 a; a.x = (_Float16)v.x; a.y = (_Float16)v.y;
            h2 c2; c2.x = (_Float16)v.z; c2.y = (_Float16)v.w;
            w2[2*k4] = a; w2[2*k4+1] = c2;
        }
    }
    const float bg = bhh[gate];
    // activation constants: sigmoid for i/f/o, tanh = 2*sigmoid(2x)-1 for g
    const float s_ = (gt == 2) ? 2.f : 1.f;
    const float a_ = (gt == 2) ? 2.f : 1.f;
    const float d_ = (gt == 2) ? -1.f : 0.f;

    __shared__ unsigned int h2b0[64];     // packed h pairs, buffer 0
    __shared__ unsigned int h2b1[64];     // buffer 1
    __shared__ float h_final[LH];         // fp32 h for epilogue
    if (t < 64) h2b0[t] = 0u;
    float c = 0.f;
    __syncthreads();

    float xv = xp[(size_t)b * G4 + t];    // t=0 slice

    auto step = [&](const unsigned int* hb, unsigned int* hw, int ts) {
        const int tn = (ts + 1 < TT) ? ts + 1 : ts;
        const float xv_next = xp[((size_t)tn * BB + b) * G4 + t];

        float a0 = 0.f, a1 = 0.f, a2 = 0.f, a3 = 0.f;
        const uint4* hb4 = (const uint4*)hb;
        #pragma unroll
        for (int k = 0; k < 16; k += 4) {
            uint4 u0 = hb4[k], u1 = hb4[k+1], u2 = hb4[k+2], u3 = hb4[k+3];
            a0 = fdot2_(as_h2(u0.x), w2[4*k+ 0], a0);
            a0 = fdot2_(as_h2(u0.y), w2[4*k+ 1], a0);
            a0 = fdot2_(as_h2(u0.z), w2[4*k+ 2], a0);
            a0 = fdot2_(as_h2(u0.w), w2[4*k+ 3], a0);
            a1 = fdot2_(as_h2(u1.x), w2[4*k+ 4], a1);
            a1 = fdot2_(as_h2(u1.y), w2[4*k+ 5], a1);
            a1 = fdot2_(as_h2(u1.z), w2[4*k+ 6], a1);
            a1 = fdot2_(as_h2(u1.w), w2[4*k+ 7], a1);
            a2 = fdot2_(as_h2(u2.x), w2[4*k+ 8], a2);
            a2 = fdot2_(as_h2(u2.y), w2[4*k+ 9], a2);
            a2 = fdot2_(as_h2(u2.z), w2[4*k+10], a2);
            a2 = fdot2_(as_h2(u2.w), w2[4*k+11], a2);
            a3 = fdot2_(as_h2(u3.x), w2[4*k+12], a3);
            a3 = fdot2_(as_h2(u3.y), w2[4*k+13], a3);
            a3 = fdot2_(as_h2(u3.z), w2[4*k+14], a3);
            a3 = fdot2_(as_h2(u3.w), w2[4*k+15], a3);
        }
        float acc = xv + bg + ((a0 + a1) + (a2 + a3));

        // branch-free activation
        float act = fmaf(a_, __fdividef(1.f, 1.f + __expf(-s_ * acc)), d_);

        // in-wave gate exchange: gate q lives at v[q ^ gt]
        float v0 = act;
        float v1 = __shfl_xor(v0, 1);
        float v2 = __shfl_xor(v0, 2);
        float v3 = __shfl_xor(v1, 2);
        float iv = (gt==0)?v0:(gt==1)?v1:(gt==2)?v2:v3;
        float fv = (gt==1)?v0:(gt==0)?v1:(gt==3)?v2:v3;
        float gv = (gt==2)?v0:(gt==3)?v1:(gt==0)?v2:v3;
        float ov = (gt==3)?v0:(gt==2)?v1:(gt==1)?v2:v3;

        c = fmaf(fv, c, iv * gv);
        float hval = ov * tanh_fast(c);

        // pack pair (j even: own + unit j+1 via shfl over distance 4)
        float hpart = __shfl_xor(hval, 4);
        if ((t & 7) == 0) {     // gt==0 && even j
            h2 p; p.x = (_Float16)hval; p.y = (_Float16)hpart;
            hw[j >> 1] = as_u32(p);
        }
        if (gt == 0) h_final[j] = hval;
        __syncthreads();

        xv = xv_next;
    };

    for (int ts = 0; ts < TT; ts += 2) {
        step(h2b0, h2b1, ts);
        step(h2b1, h2b0, ts + 1);
    }

    // epilogue: layernorm over h (128) + fc -> out[b]
    if (t < 64) {
        float h0 = h_final[t], h1 = h_final[t + 64];
        float s1 = h0 + h1, s2 = h0*h0 + h1*h1;
        #pragma unroll
        for (int off = 32; off >= 1; off >>= 1) {
            s1 += __shfl_xor(s1, off);
            s2 += __shfl_xor(s2, off);
        }
        float mu  = s1 * (1.f/128.f);
        float var = s2 * (1.f/128.f) - mu * mu;
        float r   = rsqrtf(var + 1e-5f);
        float p = ((h0 - mu)*r*lnS[t]      + lnB[t])      * fcW[t]
                + ((h1 - mu)*r*lnS[t + 64] + lnB[t + 64]) * fcW[t + 64];
        #pragma unroll
        for (int off = 32; off >= 1; off >>= 1) p += __shfl_xor(p, off);
        if (t == 0) out[b] = p + fcb[0];
    }
}

extern "C" void kernel_launch(void* const* d_in, const int* in_sizes, int n_in,
                              void* d_out, int out_size, void* d_ws, size_t ws_size,
                              hipStream_t stream) {
    const float* x     = (const float*)d_in[0];
    const float* ea    = (const float*)d_in[1];
    const float* xseq  = (const float*)d_in[2];
    const float* linW  = (const float*)d_in[3];
    const float* linB  = (const float*)d_in[4];
    const float* mW1   = (const float*)d_in[5];
    const float* mb1   = (const float*)d_in[6];
    const float* mW2   = (const float*)d_in[7];
    const float* mb2   = (const float*)d_in[8];
    const float* eps   = (const float*)d_in[9];
    const float* lnS   = (const float*)d_in[10];
    const float* lnB   = (const float*)d_in[11];
    const float* Wih   = (const float*)d_in[12];
    const float* Whh   = (const float*)d_in[13];
    const float* bih   = (const float*)d_in[14];
    const float* bhh   = (const float*)d_in[15];
    const float* llnS  = (const float*)d_in[16];
    const float* llnB  = (const float*)d_in[17];
    const float* fcW   = (const float*)d_in[18];
    const float* fcb   = (const float*)d_in[19];
    const int*   eidx  = (const int*)d_in[20];
    const int*   nidx  = (const int*)d_in[21];
    float* out = (float*)d_out;

    const int* srcs = eidx;
    const int* dsts = eidx + NE;

    // workspace layout
    float* ws   = (float*)d_ws;
    float* agg  = ws;                              // NN*64
    float* h1   = agg  + (size_t)NN * HID;
    float* h2m  = h1   + (size_t)NN * HID;
    float* selp = h2m  + (size_t)NN * HID;         // BB*G4
    float* W2T  = selp + (size_t)BB * G4;          // 32*G4
    float* xp   = W2T  + (size_t)32 * G4;          // TT*BB*G4
    int*   deg    = (int*)(xp + (size_t)TT * BB * G4);  // NN
    int*   rowptr = deg + NN;                      // NN+1
    int*   head   = rowptr + NN + 2;               // NN
    int*   loc    = head + NN;                     // NN
    int*   bsum   = loc + NN;                      // SCB
    int*   boff   = bsum + SCB + 3;                // SCB
    int*   perm   = boff + SCB + 3;                // NE
    int*   ssrc   = perm + NE;                     // NE
    uintptr_t ep = (uintptr_t)(ssrc + NE);
    ep = (ep + 15) & ~(uintptr_t)15;
    ushort4* easort = (ushort4*)ep;                // NE*16 ushort4 = 102.4 MB

    // ---- CSR build + ea permute (shared by both layers) ----
    hipMemsetAsync(deg, 0, (size_t)NN * sizeof(int), stream);
    hist_kernel<<<(NE + 255) / 256, 256, 0, stream>>>(dsts, deg);
    scan1_kernel<<<SCB, 512, 0, stream>>>(deg, loc, bsum);
    scan2_kernel<<<1, 1, 0, stream>>>(bsum, boff, rowptr);
    scan3_kernel<<<SCB, 512, 0, stream>>>(loc, boff, rowptr, head);
    scatter_kernel<<<(NE + 255) / 256, 256, 0, stream>>>(srcs, dsts, head, perm, ssrc);
    permute_kernel<<<NE / 16, 256, 0, stream>>>(ea, perm, easort);

    // ---- layer 0 ----
    edge_agg_kernel<<<2048, 256, 0, stream>>>(x, easort, linW, linB, rowptr, ssrc, agg);
    node_kernel<<<512, 256, 0, stream>>>(x, agg, mW1, mb1, mW2, mb2, eps, lnS, lnB, h1);
    // ---- layer 1 ----
    edge_agg_kernel<<<2048, 256, 0, stream>>>(h1, easort, linW + 64*64, linB + 64, rowptr, ssrc, agg);
    node_kernel<<<512, 256, 0, stream>>>(h1, agg, mW1 + 64*64, mb1 + 64, mW2 + 64*64, mb2 + 64,
                                         eps + 1, lnS + 64, lnB + 64, h2m);
    // ---- LSTM input projection (permuted to lstm thread order) ----
    prep_kernel<<<BB + 1, 512, 0, stream>>>(Wih, bih, h2m, nidx, W2T, selp);
    xp_kernel<<<TT * BB, 512, 0, stream>>>(xseq, selp, W2T, xp);
    // ---- LSTM recurrence + head ----
    lstm_kernel<<<BB, 512, 0, stream>>>(xp, Whh, bhh, llnS, llnB, fcW, fcb, out);
}